// Round 1
// baseline (237.385 us; speedup 1.0000x reference)
//
#include <hip/hip_runtime.h>
#include <hip/hip_bf16.h>
#include <math.h>

typedef unsigned short u16;

#define NVOXEL 32768
#define NPOS   4000
#define NTOT   8000
#define NPADR  8064        // 63 * 128
#define NBLK   63
#define FEATD  128
#define LDP    136         // padded bf16 row stride (128 + 8) -> 272 B rows, 16B aligned
#define TILE   128
#define TILE_CH 2176       // 128*136*2 / 16  (16-byte chunks per tile)
#define INVT   14.2857142857142857f
#define MSE_N  4194304

typedef float  f32x4  __attribute__((ext_vector_type(4)));
typedef __bf16 bf16x8 __attribute__((ext_vector_type(8)));

__device__ __forceinline__ void load_lds16(const void* g, void* l) {
  __builtin_amdgcn_global_load_lds(
      (const __attribute__((address_space(1))) unsigned int*)g,
      (__attribute__((address_space(3))) unsigned int*)l, 16, 0, 0);
}

// ---------------- gather + L2-normalize rows -> bf16 P [NPADR x LDP] ----------------
__global__ __launch_bounds__(128) void gather_norm_k(
    const float* __restrict__ Zs, const int* __restrict__ pos,
    const int* __restrict__ neg, u16* __restrict__ P) {
  int row = blockIdx.x;           // 0..7999
  int f   = threadIdx.x;          // 0..127
  int v   = (row < NPOS) ? pos[row] : neg[row - NPOS];
  float x = Zs[((size_t)f << 15) + v];       // Zs[0, f, v]
  float s = x * x;
  #pragma unroll
  for (int o = 1; o < 64; o <<= 1) s += __shfl_xor(s, o, 64);
  __shared__ float red[2];
  if ((f & 63) == 0) red[f >> 6] = s;
  __syncthreads();
  float tot = red[0] + red[1];
  float p = x / fmaxf(sqrtf(tot), 1e-12f);
  __hip_bfloat16 h = __float2bfloat16(p);
  P[(size_t)row * LDP + f] = *(u16*)&h;
}

// ---------------- shared GEMM core (128x128 tile, K=128, bf16 MFMA 16x16x32) --------
#define GEMM_CORE(P_, BI_, BJ_)                                              \
  __shared__ __align__(16) u16 As[TILE * LDP];                               \
  __shared__ __align__(16) u16 Bs[TILE * LDP];                               \
  int tid = threadIdx.x;                                                     \
  {                                                                          \
    const u16* gA = (P_) + (size_t)(BI_) * TILE * LDP;                       \
    const u16* gB = (P_) + (size_t)(BJ_) * TILE * LDP;                       \
    _Pragma("unroll")                                                        \
    for (int it = 0; it < 9; ++it) {                                         \
      int c = it * 256 + tid;                                                \
      if (c < TILE_CH) {                                                     \
        load_lds16(gA + c * 8, &As[c * 8]);                                  \
        load_lds16(gB + c * 8, &Bs[c * 8]);                                  \
      }                                                                      \
    }                                                                        \
  }                                                                          \
  __syncthreads();                                                           \
  int wave = tid >> 6, lane = tid & 63;                                      \
  int wm = (wave >> 1) << 6, wn = (wave & 1) << 6;                           \
  int r = lane & 15, q = lane >> 4;                                          \
  f32x4 acc[4][4];                                                           \
  _Pragma("unroll")                                                          \
  for (int a_ = 0; a_ < 4; ++a_)                                             \
    _Pragma("unroll")                                                        \
    for (int b_ = 0; b_ < 4; ++b_) {                                         \
      acc[a_][b_][0] = 0.f; acc[a_][b_][1] = 0.f;                            \
      acc[a_][b_][2] = 0.f; acc[a_][b_][3] = 0.f;                            \
    }                                                                        \
  _Pragma("unroll")                                                          \
  for (int kk = 0; kk < 4; ++kk) {                                           \
    int k0 = kk * 32 + q * 8;                                                \
    bf16x8 af[4], bfr[4];                                                    \
    _Pragma("unroll")                                                        \
    for (int t = 0; t < 4; ++t) {                                            \
      af[t]  = *(const bf16x8*)&As[(wm + t * 16 + r) * LDP + k0];            \
      bfr[t] = *(const bf16x8*)&Bs[(wn + t * 16 + r) * LDP + k0];            \
    }                                                                        \
    _Pragma("unroll")                                                        \
    for (int mt = 0; mt < 4; ++mt)                                           \
      _Pragma("unroll")                                                      \
      for (int nt = 0; nt < 4; ++nt)                                         \
        acc[mt][nt] = __builtin_amdgcn_mfma_f32_16x16x32_bf16(               \
            af[mt], bfr[nt], acc[mt][nt], 0, 0, 0);                          \
  }

// ---------------- pass 1: rowsq[i] = sum_j (dot[i,j]/T)^2 ----------------
__global__ __launch_bounds__(256, 2) void pass1_k(
    const u16* __restrict__ P, float* __restrict__ rowsq) {
  int bi = blockIdx.x, bj = blockIdx.y;
  GEMM_CORE(P, bi, bj)
  // C/D layout: row = q*4+reg (+ tile offsets), col = r (+ tile offsets)
  int i0 = bi * TILE + wm + q * 4;
  int j0 = bj * TILE + wn + r;
  float rs[4][4];
  #pragma unroll
  for (int mt = 0; mt < 4; ++mt)
    #pragma unroll
    for (int reg = 0; reg < 4; ++reg) {
      float s = 0.f;
      #pragma unroll
      for (int nt = 0; nt < 4; ++nt) {
        int j = j0 + nt * 16;
        if (j < NTOT) { float d = acc[mt][nt][reg] * INVT; s += d * d; }
      }
      rs[mt][reg] = s;
    }
  #pragma unroll
  for (int o = 1; o < 16; o <<= 1)
    #pragma unroll
    for (int mt = 0; mt < 4; ++mt)
      #pragma unroll
      for (int reg = 0; reg < 4; ++reg)
        rs[mt][reg] += __shfl_xor(rs[mt][reg], o, 64);
  if (r == 0) {
    #pragma unroll
    for (int mt = 0; mt < 4; ++mt)
      #pragma unroll
      for (int reg = 0; reg < 4; ++reg) {
        int i = i0 + mt * 16 + reg;
        if (i < NTOT) atomicAdd(&rowsq[i], rs[mt][reg]);
      }
  }
}

// ---------------- rowinv ----------------
__global__ __launch_bounds__(256) void rowinv_k(const float* __restrict__ rowsq,
                                                float* __restrict__ rowinv) {
  int i = blockIdx.x * 256 + threadIdx.x;
  if (i < NPADR) rowinv[i] = 1.0f / fmaxf(sqrtf(rowsq[i]), 1e-12f);
}

// ---------------- pass 2: denom[i] += exp(dnorm) (diff label), S += dnorm (same) ----
__global__ __launch_bounds__(256, 2) void pass2_k(
    const u16* __restrict__ P, const float* __restrict__ rowinv,
    float* __restrict__ denom, float* __restrict__ Sacc) {
  int bi = blockIdx.x, bj = blockIdx.y;
  GEMM_CORE(P, bi, bj)
  int i0 = bi * TILE + wm + q * 4;
  int j0 = bj * TILE + wn + r;
  float rinv[4][4];
  #pragma unroll
  for (int mt = 0; mt < 4; ++mt)
    #pragma unroll
    for (int reg = 0; reg < 4; ++reg) {
      int i = i0 + mt * 16 + reg;
      rinv[mt][reg] = (i < NTOT) ? rowinv[i] : 0.f;
    }
  float smask = 0.f;
  float de[4][4];
  #pragma unroll
  for (int mt = 0; mt < 4; ++mt)
    #pragma unroll
    for (int reg = 0; reg < 4; ++reg) {
      int i = i0 + mt * 16 + reg;
      bool iv = i < NTOT;
      bool li = i < NPOS;
      float sc = INVT * rinv[mt][reg];
      float s = 0.f;
      #pragma unroll
      for (int nt = 0; nt < 4; ++nt) {
        int j = j0 + nt * 16;
        if (iv && j < NTOT) {
          float d = acc[mt][nt][reg] * sc;
          if (li == (j < NPOS)) {
            if (i != j) smask += d;     // log(exp(d)) = d on the class mask
          } else {
            s += __expf(d);             // denominator: different-label only
          }
        }
      }
      de[mt][reg] = s;
    }
  #pragma unroll
  for (int o = 1; o < 16; o <<= 1)
    #pragma unroll
    for (int mt = 0; mt < 4; ++mt)
      #pragma unroll
      for (int reg = 0; reg < 4; ++reg)
        de[mt][reg] += __shfl_xor(de[mt][reg], o, 64);
  if (r == 0) {
    #pragma unroll
    for (int mt = 0; mt < 4; ++mt)
      #pragma unroll
      for (int reg = 0; reg < 4; ++reg) {
        int i = i0 + mt * 16 + reg;
        if (i < NTOT && de[mt][reg] != 0.f) atomicAdd(&denom[i], de[mt][reg]);
      }
  }
  #pragma unroll
  for (int o = 1; o < 64; o <<= 1) smask += __shfl_xor(smask, o, 64);
  __shared__ float sred[4];
  if (lane == 0) sred[wave] = smask;
  __syncthreads();
  if (tid == 0) {
    float t = sred[0] + sred[1] + sred[2] + sred[3];
    if (t != 0.f) atomicAdd(Sacc, t);
  }
}

// ---------------- MSE ----------------
__global__ __launch_bounds__(256) void mse_k(const float4* __restrict__ a,
                                             const float4* __restrict__ b,
                                             float* __restrict__ acc) {
  int tid = threadIdx.x;
  float s = 0.f;
  for (size_t idx = (size_t)blockIdx.x * 256 + tid; idx < (MSE_N / 4);
       idx += (size_t)gridDim.x * 256) {
    float4 u = a[idx], w = b[idx];
    float dx = u.x - w.x, dy = u.y - w.y, dz = u.z - w.z, dv = u.w - w.w;
    s += dx * dx + dy * dy + dz * dz + dv * dv;
  }
  #pragma unroll
  for (int o = 1; o < 64; o <<= 1) s += __shfl_xor(s, o, 64);
  __shared__ float red[4];
  if ((tid & 63) == 0) red[tid >> 6] = s;
  __syncthreads();
  if (tid == 0) atomicAdd(acc, red[0] + red[1] + red[2] + red[3]);
}

// ---------------- final combine ----------------
__global__ __launch_bounds__(256) void final_k(const float* __restrict__ denom,
                                               const float* __restrict__ Sacc,
                                               const float* __restrict__ mseacc,
                                               float* __restrict__ out) {
  int tid = threadIdx.x;
  float s = 0.f;
  for (int i = tid; i < NTOT; i += 256) s += logf(denom[i]);
  #pragma unroll
  for (int o = 1; o < 64; o <<= 1) s += __shfl_xor(s, o, 64);
  __shared__ float red[4];
  if ((tid & 63) == 0) red[tid >> 6] = s;
  __syncthreads();
  if (tid == 0) {
    float logsum = red[0] + red[1] + red[2] + red[3];
    float supcon = logsum - Sacc[0] * (1.0f / (float)NTOT);
    out[0] = supcon + 0.5f * (mseacc[0] * (1.0f / (float)MSE_N));
  }
}

extern "C" void kernel_launch(void* const* d_in, const int* in_sizes, int n_in,
                              void* d_out, int out_size, void* d_ws, size_t ws_size,
                              hipStream_t stream) {
  const float* Zs  = (const float*)d_in[0];
  const int*   pos = (const int*)d_in[1];
  const int*   neg = (const int*)d_in[2];
  const float* fd  = (const float*)d_in[3];
  const float* idf = (const float*)d_in[4];
  float* out = (float*)d_out;

  char* ws = (char*)d_ws;
  u16*   P      = (u16*)ws;
  size_t off    = (size_t)NPADR * LDP * sizeof(u16);   // 2,193,408 B
  float* rowsq  = (float*)(ws + off); off += NPADR * 4;
  float* rowinv = (float*)(ws + off); off += NPADR * 4;
  float* denom  = (float*)(ws + off); off += NPADR * 4;
  float* Sacc   = (float*)(ws + off); off += 4;
  float* mseacc = (float*)(ws + off); off += 4;

  hipMemsetAsync(d_ws, 0, off, stream);
  gather_norm_k<<<NTOT, 128, 0, stream>>>(Zs, pos, neg, P);
  dim3 g(NBLK, NBLK);
  pass1_k<<<g, 256, 0, stream>>>(P, rowsq);
  rowinv_k<<<(NPADR + 255) / 256, 256, 0, stream>>>(rowsq, rowinv);
  pass2_k<<<g, 256, 0, stream>>>(P, rowinv, denom, Sacc);
  mse_k<<<1024, 256, 0, stream>>>((const float4*)fd, (const float4*)idf, mseacc);
  final_k<<<1, 256, 0, stream>>>(denom, Sacc, mseacc, out);
}

// Round 2
// 210.000 us; speedup vs baseline: 1.1304x; 1.1304x over previous
//
#include <hip/hip_runtime.h>
#include <hip/hip_bf16.h>
#include <math.h>

typedef unsigned short u16;
typedef float  f32x4  __attribute__((ext_vector_type(4)));
typedef __bf16 bf16x8 __attribute__((ext_vector_type(8)));

#define NPOS   4000
#define NNEG   4000
#define PCOLS  8192      // padded cols: pos 0..4095, neg 4096..8191
#define LDP    136       // padded bf16 row stride (16B-aligned rows)
#define TILE_CH 2176     // 128*136*2/16 16-byte chunks per 128-row tile
#define MSE_N  4194304

__device__ __forceinline__ void load_lds16(const void* g, void* l) {
  __builtin_amdgcn_global_load_lds(
      (const __attribute__((address_space(1))) unsigned int*)g,
      (__attribute__((address_space(3))) unsigned int*)l, 16, 0, 0);
}

__device__ __forceinline__ float bf2f(u16 h) {
  unsigned u = ((unsigned)h) << 16;
  return __builtin_bit_cast(float, u);
}

// ---- gather + L2-normalize -> Pc [64 chunks][128 f][136 s] and Prow [8192][136] ----
__global__ __launch_bounds__(128) void gather_norm_k(
    const float* __restrict__ Zs, const int* __restrict__ pos,
    const int* __restrict__ neg, u16* __restrict__ Pc, u16* __restrict__ Prow) {
  int row = blockIdx.x;                       // 0..7999
  int f   = threadIdx.x;                      // 0..127
  int col = (row < NPOS) ? row : (4096 + row - NPOS);
  int v   = (row < NPOS) ? pos[row] : neg[row - NPOS];
  float x = Zs[((size_t)f << 15) + v];
  float s = x * x;
  #pragma unroll
  for (int o = 1; o < 64; o <<= 1) s += __shfl_xor(s, o, 64);
  __shared__ float red[2];
  if ((f & 63) == 0) red[f >> 6] = s;
  __syncthreads();
  float tot = red[0] + red[1];
  float p = x / fmaxf(sqrtf(tot), 1e-12f);
  __hip_bfloat16 h = __float2bfloat16(p);
  u16 hb = *(u16*)&h;
  Prow[(size_t)col * LDP + f] = hb;
  Pc[(size_t)(col >> 7) * (128 * LDP) + (size_t)f * LDP + (col & 127)] = hb;
}

// ---- SYRK: partial G for 4 sample-chunks per block (16 blocks; b<8 pos, b>=8 neg) ----
__global__ __launch_bounds__(256) void gsyrk_k(const u16* __restrict__ Pc,
                                               float* __restrict__ Gpart) {
  __shared__ __align__(16) u16 T[128 * LDP];
  int b = blockIdx.x, tid = threadIdx.x;
  int wave = tid >> 6, lane = tid & 63;
  int wm = (wave >> 1) << 6, wn = (wave & 1) << 6;
  int r = lane & 15, q = lane >> 4;
  f32x4 acc[4][4];
  #pragma unroll
  for (int a = 0; a < 4; ++a)
    #pragma unroll
    for (int c = 0; c < 4; ++c) {
      acc[a][c][0] = 0.f; acc[a][c][1] = 0.f; acc[a][c][2] = 0.f; acc[a][c][3] = 0.f;
    }
  for (int it = 0; it < 4; ++it) {
    const u16* g = Pc + (size_t)(b * 4 + it) * (128 * LDP);
    #pragma unroll
    for (int k = 0; k < 9; ++k) {
      int cc = k * 256 + tid;
      if (cc < TILE_CH) load_lds16(g + cc * 8, &T[cc * 8]);
    }
    __syncthreads();
    #pragma unroll
    for (int kk = 0; kk < 4; ++kk) {
      int k0 = kk * 32 + q * 8;
      bf16x8 af[4], bfr[4];
      #pragma unroll
      for (int t = 0; t < 4; ++t) {
        af[t]  = *(const bf16x8*)&T[(wm + t * 16 + r) * LDP + k0];
        bfr[t] = *(const bf16x8*)&T[(wn + t * 16 + r) * LDP + k0];
      }
      #pragma unroll
      for (int mt = 0; mt < 4; ++mt)
        #pragma unroll
        for (int nt = 0; nt < 4; ++nt)
          acc[mt][nt] = __builtin_amdgcn_mfma_f32_16x16x32_bf16(
              af[mt], bfr[nt], acc[mt][nt], 0, 0, 0);
    }
    __syncthreads();
  }
  float* gp = Gpart + (size_t)b * 16384;
  #pragma unroll
  for (int mt = 0; mt < 4; ++mt)
    #pragma unroll
    for (int nt = 0; nt < 4; ++nt)
      #pragma unroll
      for (int reg = 0; reg < 4; ++reg) {
        int a = wm + mt * 16 + q * 4 + reg;
        int bc = wn + nt * 16 + r;
        gp[a * 128 + bc] = acc[mt][nt][reg];
      }
}

// ---- reduce partials -> Gbf [2][128][136] bf16 ; blocks 128/129 compute S [2][128] ----
__global__ __launch_bounds__(256) void reduceGS_k(const float* __restrict__ Gpart,
                                                  const u16* __restrict__ Pc,
                                                  u16* __restrict__ Gbf,
                                                  float* __restrict__ S) {
  int blk = blockIdx.x, tid = threadIdx.x;
  if (blk < 128) {
    int idx = blk * 256 + tid;           // 0..32767
    int set = idx >> 14, e = idx & 16383;
    float sum = 0.f;
    #pragma unroll
    for (int p = 0; p < 8; ++p) sum += Gpart[(size_t)(set * 8 + p) * 16384 + e];
    __hip_bfloat16 h = __float2bfloat16(sum);
    Gbf[(size_t)set * (128 * LDP) + (size_t)(e >> 7) * LDP + (e & 127)] = *(u16*)&h;
  } else {
    int set = blk - 128;
    int f = tid >> 1, half = tid & 1;
    float sum = 0.f;
    for (int cc = 0; cc < 16; ++cc) {
      int ch = set * 32 + half * 16 + cc;
      const u16* base = Pc + (size_t)ch * (128 * LDP) + (size_t)f * LDP;
      #pragma unroll
      for (int vb = 0; vb < 16; ++vb)
        #pragma unroll
        for (int j = 0; j < 8; ++j) sum += bf2f(base[vb * 8 + j]);
    }
    sum += __shfl_xor(sum, 1, 64);
    if (half == 0) S[set * 128 + f] = sum;
  }
}

// ---- quadratic forms q_set[i] = p_i^T G_set p_i  (+ S-dots from set==0 blocks) ----
__global__ __launch_bounds__(256) void quad_k(
    const u16* __restrict__ Gbf, const u16* __restrict__ Prow,
    const float* __restrict__ Sg, float* __restrict__ qpos, float* __restrict__ qneg,
    float* __restrict__ sdpos, float* __restrict__ sdneg) {
  __shared__ __align__(16) u16 Gs[128 * LDP];
  __shared__ __align__(16) u16 Ps[128 * LDP];
  __shared__ float Sl[256];
  int cb = blockIdx.x, set = blockIdx.y, tid = threadIdx.x;
  Sl[tid] = Sg[tid];
  const u16* gG = Gbf + (size_t)set * (128 * LDP);
  const u16* gP = Prow + (size_t)cb * (128 * LDP);
  #pragma unroll
  for (int k = 0; k < 9; ++k) {
    int cc = k * 256 + tid;
    if (cc < TILE_CH) {
      load_lds16(gG + cc * 8, &Gs[cc * 8]);
      load_lds16(gP + cc * 8, &Ps[cc * 8]);
    }
  }
  __syncthreads();
  int wave = tid >> 6, lane = tid & 63;
  int wm = (wave >> 1) << 6, wn = (wave & 1) << 6;
  int r = lane & 15, q = lane >> 4;
  f32x4 acc[4][4];
  #pragma unroll
  for (int a = 0; a < 4; ++a)
    #pragma unroll
    for (int c = 0; c < 4; ++c) {
      acc[a][c][0] = 0.f; acc[a][c][1] = 0.f; acc[a][c][2] = 0.f; acc[a][c][3] = 0.f;
    }
  #pragma unroll
  for (int kk = 0; kk < 4; ++kk) {
    int k0 = kk * 32 + q * 8;
    bf16x8 af[4], bfr[4];
    #pragma unroll
    for (int t = 0; t < 4; ++t) {
      af[t]  = *(const bf16x8*)&Gs[(wm + t * 16 + r) * LDP + k0];
      bfr[t] = *(const bf16x8*)&Ps[(wn + t * 16 + r) * LDP + k0];
    }
    #pragma unroll
    for (int mt = 0; mt < 4; ++mt)
      #pragma unroll
      for (int nt = 0; nt < 4; ++nt)
        acc[mt][nt] = __builtin_amdgcn_mfma_f32_16x16x32_bf16(
            af[mt], bfr[nt], acc[mt][nt], 0, 0, 0);
  }
  // q epilogue: Y[a][i] dotted with P[i][a], reduced over a
  float qv[4] = {0.f, 0.f, 0.f, 0.f};
  #pragma unroll
  for (int nt = 0; nt < 4; ++nt) {
    int il = wn + nt * 16 + r;
    #pragma unroll
    for (int mt = 0; mt < 4; ++mt) {
      const u16* pp = &Ps[il * LDP + wm + mt * 16 + q * 4];
      #pragma unroll
      for (int reg = 0; reg < 4; ++reg)
        qv[nt] += acc[mt][nt][reg] * bf2f(pp[reg]);
    }
  }
  #pragma unroll
  for (int nt = 0; nt < 4; ++nt) {
    qv[nt] += __shfl_xor(qv[nt], 16, 64);
    qv[nt] += __shfl_xor(qv[nt], 32, 64);
  }
  float* qarr = set ? qneg : qpos;
  if (q == 0) {
    #pragma unroll
    for (int nt = 0; nt < 4; ++nt)
      atomicAdd(&qarr[cb * 128 + wn + nt * 16 + r], qv[nt]);
  }
  // S-dots (only set==0 blocks): sd_pos[i], sd_neg[i]
  if (set == 0) {
    int which = tid >> 7, sl = tid & 127;
    const float* Sv = &Sl[which * 128];
    float d = 0.f;
    #pragma unroll
    for (int fb = 0; fb < 16; ++fb) {
      const u16* pv = &Ps[sl * LDP + fb * 8];
      #pragma unroll
      for (int j = 0; j < 8; ++j) d += Sv[fb * 8 + j] * bf2f(pv[j]);
    }
    (which ? sdneg : sdpos)[cb * 128 + sl] = d;
  }
}

// ---- per-sample: log denom (2nd-order), smask term; reduce to accs ----
__global__ __launch_bounds__(256) void persample_k(
    const float* __restrict__ qpos, const float* __restrict__ qneg,
    const float* __restrict__ sdpos, const float* __restrict__ sdneg,
    float* __restrict__ accs) {
  int col = blockIdx.x * 256 + threadIdx.x;   // 0..8191
  float lg = 0.f, sm = 0.f;
  bool isp = col < NPOS;
  bool isn = (col >= 4096) && (col < 4096 + NNEG);
  if (isp || isn) {
    float qp = qpos[col], qn = qneg[col];
    float c = 1.0f / sqrtf(qp + qn);
    float qo  = isp ? qn : qp;
    float sdo = isp ? sdneg[col] : sdpos[col];
    float sds = isp ? sdpos[col] : sdneg[col];
    float denom = 4000.0f + c * sdo + 0.5f * c * c * qo;
    lg = logf(denom);
    sm = c * (sds - 1.0f);
  }
  int tid = threadIdx.x;
  #pragma unroll
  for (int o = 1; o < 64; o <<= 1) {
    lg += __shfl_xor(lg, o, 64);
    sm += __shfl_xor(sm, o, 64);
  }
  __shared__ float rl[4], rs[4];
  if ((tid & 63) == 0) { rl[tid >> 6] = lg; rs[tid >> 6] = sm; }
  __syncthreads();
  if (tid == 0) {
    atomicAdd(&accs[0], rl[0] + rl[1] + rl[2] + rl[3]);
    atomicAdd(&accs[1], rs[0] + rs[1] + rs[2] + rs[3]);
  }
}

// ---- MSE ----
__global__ __launch_bounds__(256) void mse_k(const float4* __restrict__ a,
                                             const float4* __restrict__ b,
                                             float* __restrict__ accs) {
  int tid = threadIdx.x;
  float s = 0.f;
  for (size_t idx = (size_t)blockIdx.x * 256 + tid; idx < (MSE_N / 4);
       idx += (size_t)gridDim.x * 256) {
    float4 u = a[idx], w = b[idx];
    float dx = u.x - w.x, dy = u.y - w.y, dz = u.z - w.z, dv = u.w - w.w;
    s += dx * dx + dy * dy + dz * dz + dv * dv;
  }
  #pragma unroll
  for (int o = 1; o < 64; o <<= 1) s += __shfl_xor(s, o, 64);
  __shared__ float red[4];
  if ((tid & 63) == 0) red[tid >> 6] = s;
  __syncthreads();
  if (tid == 0) atomicAdd(&accs[2], red[0] + red[1] + red[2] + red[3]);
}

// ---- final combine ----
__global__ void final_k(const float* __restrict__ accs, float* __restrict__ out) {
  if (threadIdx.x == 0)
    out[0] = accs[0] - accs[1] * (1.0f / 8000.0f)
           + 0.5f * (accs[2] * (1.0f / (float)MSE_N));
}

extern "C" void kernel_launch(void* const* d_in, const int* in_sizes, int n_in,
                              void* d_out, int out_size, void* d_ws, size_t ws_size,
                              hipStream_t stream) {
  const float* Zs  = (const float*)d_in[0];
  const int*   pos = (const int*)d_in[1];
  const int*   neg = (const int*)d_in[2];
  const float* fd  = (const float*)d_in[3];
  const float* idf = (const float*)d_in[4];
  float* out = (float*)d_out;

  char* ws = (char*)d_ws;
  u16*   Pc    = (u16*)(ws + 0);                 // 2,228,224 B
  u16*   Prow  = (u16*)(ws + 2228224);           // 2,228,224 B
  float* qpos  = (float*)(ws + 4456448);         // 32,768 B
  float* qneg  = (float*)(ws + 4489216);         // 32,768 B
  float* accs  = (float*)(ws + 4521984);         // 64 B
  u16*   Gbf   = (u16*)(ws + 4522048);           // 69,632 B
  float* Gpart = (float*)(ws + 4591680);         // 1,048,576 B
  float* S     = (float*)(ws + 5640256);         // 1,024 B
  float* sdpos = (float*)(ws + 5641280);         // 32,768 B
  float* sdneg = (float*)(ws + 5674048);         // 32,768 B -> 5,706,816 total

  // zero Pc+Prow (pad correctness) and atomic targets (qpos,qneg,accs)
  hipMemsetAsync(d_ws, 0, 4522048, stream);
  gather_norm_k<<<8000, 128, 0, stream>>>(Zs, pos, neg, Pc, Prow);
  gsyrk_k<<<16, 256, 0, stream>>>(Pc, Gpart);
  reduceGS_k<<<130, 256, 0, stream>>>(Gpart, Pc, Gbf, S);
  quad_k<<<dim3(64, 2), 256, 0, stream>>>(Gbf, Prow, S, qpos, qneg, sdpos, sdneg);
  persample_k<<<32, 256, 0, stream>>>(qpos, qneg, sdpos, sdneg, accs);
  mse_k<<<1024, 256, 0, stream>>>((const float4*)fd, (const float4*)idf, accs);
  final_k<<<1, 64, 0, stream>>>(accs, out);
}

// Round 3
// 142.578 us; speedup vs baseline: 1.6649x; 1.4729x over previous
//
#include <hip/hip_runtime.h>
#include <hip/hip_bf16.h>
#include <math.h>

typedef unsigned short u16;
typedef float  f32x4  __attribute__((ext_vector_type(4)));
typedef __bf16 bf16x8 __attribute__((ext_vector_type(8)));

#define NPOS   4000
#define NNEG   4000
#define LDP    136       // padded bf16 row stride (16B-aligned rows)
#define TILE_CH 2176     // 128*136*2/16 16-byte chunks per 128-row tile
#define MSE_N  4194304

__device__ __forceinline__ void load_lds16(const void* g, void* l) {
  __builtin_amdgcn_global_load_lds(
      (const __attribute__((address_space(1))) unsigned int*)g,
      (__attribute__((address_space(3))) unsigned int*)l, 16, 0, 0);
}

__device__ __forceinline__ float bf2f(u16 h) {
  unsigned u = ((unsigned)h) << 16;
  return __builtin_bit_cast(float, u);
}

// ---- gather + L2-normalize -> Pc [64 chunks][128 f][136 s] and Prow [8192][136] ----
__global__ __launch_bounds__(128) void gather_norm_k(
    const float* __restrict__ Zs, const int* __restrict__ pos,
    const int* __restrict__ neg, u16* __restrict__ Pc, u16* __restrict__ Prow) {
  int row = blockIdx.x;                       // 0..7999
  int f   = threadIdx.x;                      // 0..127
  int col = (row < NPOS) ? row : (4096 + row - NPOS);
  int v   = (row < NPOS) ? pos[row] : neg[row - NPOS];
  float x = Zs[((size_t)f << 15) + v];
  float s = x * x;
  #pragma unroll
  for (int o = 1; o < 64; o <<= 1) s += __shfl_xor(s, o, 64);
  __shared__ float red[2];
  if ((f & 63) == 0) red[f >> 6] = s;
  __syncthreads();
  float tot = red[0] + red[1];
  float p = x / fmaxf(sqrtf(tot), 1e-12f);
  __hip_bfloat16 h = __float2bfloat16(p);
  u16 hb = *(u16*)&h;
  Prow[(size_t)col * LDP + f] = hb;
  Pc[(size_t)(col >> 7) * (128 * LDP) + (size_t)f * LDP + (col & 127)] = hb;
}

// ---- SYRK: partial G for 4 chunks per block (16 blocks; b<8 pos, b>=8 neg) --------
// ---- also: S[set][f] = sum over samples of p[s][f], summed from the LDS tiles ----
__global__ __launch_bounds__(256) void gsyrk_k(const u16* __restrict__ Pc,
                                               float* __restrict__ Gpart,
                                               float* __restrict__ S) {
  __shared__ __align__(16) u16 T[128 * LDP];
  int b = blockIdx.x, tid = threadIdx.x;
  int wave = tid >> 6, lane = tid & 63;
  int wm = (wave >> 1) << 6, wn = (wave & 1) << 6;
  int r = lane & 15, q = lane >> 4;
  int sf = tid >> 1, shalf = tid & 1;       // S-sum assignment: thread -> (f, half)
  float ssum = 0.f;
  f32x4 acc[4][4];
  #pragma unroll
  for (int a = 0; a < 4; ++a)
    #pragma unroll
    for (int c = 0; c < 4; ++c) {
      acc[a][c][0] = 0.f; acc[a][c][1] = 0.f; acc[a][c][2] = 0.f; acc[a][c][3] = 0.f;
    }
  for (int it = 0; it < 4; ++it) {
    const u16* g = Pc + (size_t)(b * 4 + it) * (128 * LDP);
    #pragma unroll
    for (int k = 0; k < 9; ++k) {
      int cc = k * 256 + tid;
      if (cc < TILE_CH) load_lds16(g + cc * 8, &T[cc * 8]);
    }
    __syncthreads();
    #pragma unroll
    for (int kk = 0; kk < 4; ++kk) {
      int k0 = kk * 32 + q * 8;
      bf16x8 af[4], bfr[4];
      #pragma unroll
      for (int t = 0; t < 4; ++t) {
        af[t]  = *(const bf16x8*)&T[(wm + t * 16 + r) * LDP + k0];
        bfr[t] = *(const bf16x8*)&T[(wn + t * 16 + r) * LDP + k0];
      }
      #pragma unroll
      for (int mt = 0; mt < 4; ++mt)
        #pragma unroll
        for (int nt = 0; nt < 4; ++nt)
          acc[mt][nt] = __builtin_amdgcn_mfma_f32_16x16x32_bf16(
              af[mt], bfr[nt], acc[mt][nt], 0, 0, 0);
    }
    // S partial: sum 64 contiguous samples of feature sf from the staged tile
    {
      const u16* base = &T[sf * LDP + shalf * 64];
      #pragma unroll
      for (int vb = 0; vb < 8; ++vb) {
        bf16x8 v = *(const bf16x8*)&base[vb * 8];
        #pragma unroll
        for (int j = 0; j < 8; ++j) ssum += (float)v[j];
      }
    }
    __syncthreads();
  }
  float* gp = Gpart + (size_t)b * 16384;
  #pragma unroll
  for (int mt = 0; mt < 4; ++mt)
    #pragma unroll
    for (int nt = 0; nt < 4; ++nt)
      #pragma unroll
      for (int reg = 0; reg < 4; ++reg) {
        int a = wm + mt * 16 + q * 4 + reg;
        int bc = wn + nt * 16 + r;
        gp[a * 128 + bc] = acc[mt][nt][reg];
      }
  ssum += __shfl_xor(ssum, 1, 64);
  if (shalf == 0) atomicAdd(&S[(b >> 3) * 128 + sf], ssum);
}

// ---- reduce Gpart partials -> Gbf [2][128][136] bf16 ----
__global__ __launch_bounds__(256) void reduceG_k(const float* __restrict__ Gpart,
                                                 u16* __restrict__ Gbf) {
  int idx = blockIdx.x * 256 + threadIdx.x;  // 0..32767
  int set = idx >> 14, e = idx & 16383;
  float sum = 0.f;
  #pragma unroll
  for (int p = 0; p < 8; ++p) sum += Gpart[(size_t)(set * 8 + p) * 16384 + e];
  __hip_bfloat16 h = __float2bfloat16(sum);
  Gbf[(size_t)set * (128 * LDP) + (size_t)(e >> 7) * LDP + (e & 127)] = *(u16*)&h;
}

// ---- quadratic forms q_set[i] = p_i^T G_set p_i  (+ S-dots from set==0 blocks) ----
__global__ __launch_bounds__(256) void quad_k(
    const u16* __restrict__ Gbf, const u16* __restrict__ Prow,
    const float* __restrict__ Sg, float* __restrict__ qpos, float* __restrict__ qneg,
    float* __restrict__ sdpos, float* __restrict__ sdneg) {
  __shared__ __align__(16) u16 Gs[128 * LDP];
  __shared__ __align__(16) u16 Ps[128 * LDP];
  __shared__ float Sl[256];
  int cb = blockIdx.x, set = blockIdx.y, tid = threadIdx.x;
  Sl[tid] = Sg[tid];
  const u16* gG = Gbf + (size_t)set * (128 * LDP);
  const u16* gP = Prow + (size_t)cb * (128 * LDP);
  #pragma unroll
  for (int k = 0; k < 9; ++k) {
    int cc = k * 256 + tid;
    if (cc < TILE_CH) {
      load_lds16(gG + cc * 8, &Gs[cc * 8]);
      load_lds16(gP + cc * 8, &Ps[cc * 8]);
    }
  }
  __syncthreads();
  int wave = tid >> 6, lane = tid & 63;
  int wm = (wave >> 1) << 6, wn = (wave & 1) << 6;
  int r = lane & 15, q = lane >> 4;
  f32x4 acc[4][4];
  #pragma unroll
  for (int a = 0; a < 4; ++a)
    #pragma unroll
    for (int c = 0; c < 4; ++c) {
      acc[a][c][0] = 0.f; acc[a][c][1] = 0.f; acc[a][c][2] = 0.f; acc[a][c][3] = 0.f;
    }
  #pragma unroll
  for (int kk = 0; kk < 4; ++kk) {
    int k0 = kk * 32 + q * 8;
    bf16x8 af[4], bfr[4];
    #pragma unroll
    for (int t = 0; t < 4; ++t) {
      af[t]  = *(const bf16x8*)&Gs[(wm + t * 16 + r) * LDP + k0];
      bfr[t] = *(const bf16x8*)&Ps[(wn + t * 16 + r) * LDP + k0];
    }
    #pragma unroll
    for (int mt = 0; mt < 4; ++mt)
      #pragma unroll
      for (int nt = 0; nt < 4; ++nt)
        acc[mt][nt] = __builtin_amdgcn_mfma_f32_16x16x32_bf16(
            af[mt], bfr[nt], acc[mt][nt], 0, 0, 0);
  }
  // q epilogue: Y[a][i] dotted with P[i][a], reduced over a
  float qv[4] = {0.f, 0.f, 0.f, 0.f};
  #pragma unroll
  for (int nt = 0; nt < 4; ++nt) {
    int il = wn + nt * 16 + r;
    #pragma unroll
    for (int mt = 0; mt < 4; ++mt) {
      const u16* pp = &Ps[il * LDP + wm + mt * 16 + q * 4];
      #pragma unroll
      for (int reg = 0; reg < 4; ++reg)
        qv[nt] += acc[mt][nt][reg] * bf2f(pp[reg]);
    }
  }
  #pragma unroll
  for (int nt = 0; nt < 4; ++nt) {
    qv[nt] += __shfl_xor(qv[nt], 16, 64);
    qv[nt] += __shfl_xor(qv[nt], 32, 64);
  }
  float* qarr = set ? qneg : qpos;
  if (q == 0) {
    #pragma unroll
    for (int nt = 0; nt < 4; ++nt)
      atomicAdd(&qarr[cb * 128 + wn + nt * 16 + r], qv[nt]);
  }
  // S-dots (only set==0 blocks): sd_pos[i], sd_neg[i]
  if (set == 0) {
    int which = tid >> 7, sl = tid & 127;
    const float* Sv = &Sl[which * 128];
    float d = 0.f;
    #pragma unroll
    for (int fb = 0; fb < 16; ++fb) {
      const u16* pv = &Ps[sl * LDP + fb * 8];
      #pragma unroll
      for (int j = 0; j < 8; ++j) d += Sv[fb * 8 + j] * bf2f(pv[j]);
    }
    (which ? sdneg : sdpos)[cb * 128 + sl] = d;
  }
}

// ---- MSE ----
__global__ __launch_bounds__(256) void mse_k(const float4* __restrict__ a,
                                             const float4* __restrict__ b,
                                             float* __restrict__ accs) {
  int tid = threadIdx.x;
  float s = 0.f;
  for (size_t idx = (size_t)blockIdx.x * 256 + tid; idx < (MSE_N / 4);
       idx += (size_t)gridDim.x * 256) {
    float4 u = a[idx], w = b[idx];
    float dx = u.x - w.x, dy = u.y - w.y, dz = u.z - w.z, dv = u.w - w.w;
    s += dx * dx + dy * dy + dz * dz + dv * dv;
  }
  #pragma unroll
  for (int o = 1; o < 64; o <<= 1) s += __shfl_xor(s, o, 64);
  __shared__ float red[4];
  if ((tid & 63) == 0) red[tid >> 6] = s;
  __syncthreads();
  if (tid == 0) atomicAdd(&accs[2], red[0] + red[1] + red[2] + red[3]);
}

// ---- per-sample terms + final combine (single block) ----
__global__ __launch_bounds__(1024) void persample_final_k(
    const float* __restrict__ qpos, const float* __restrict__ qneg,
    const float* __restrict__ sdpos, const float* __restrict__ sdneg,
    const float* __restrict__ accs, float* __restrict__ out) {
  int tid = threadIdx.x;
  float lg = 0.f, sm = 0.f;
  for (int col = tid; col < 8192; col += 1024) {
    bool isp = col < NPOS;
    bool isn = (col >= 4096) && (col < 4096 + NNEG);
    if (isp || isn) {
      float qp = qpos[col], qn = qneg[col];
      float c = 1.0f / sqrtf(qp + qn);
      float qo  = isp ? qn : qp;
      float sdo = isp ? sdneg[col] : sdpos[col];
      float sds = isp ? sdpos[col] : sdneg[col];
      float denom = 4000.0f + c * sdo + 0.5f * c * c * qo;
      lg += logf(denom);
      sm += c * (sds - 1.0f);
    }
  }
  #pragma unroll
  for (int o = 1; o < 64; o <<= 1) {
    lg += __shfl_xor(lg, o, 64);
    sm += __shfl_xor(sm, o, 64);
  }
  __shared__ float rl[16], rs[16];
  if ((tid & 63) == 0) { rl[tid >> 6] = lg; rs[tid >> 6] = sm; }
  __syncthreads();
  if (tid == 0) {
    float lgs = 0.f, sms = 0.f;
    #pragma unroll
    for (int w = 0; w < 16; ++w) { lgs += rl[w]; sms += rs[w]; }
    out[0] = lgs - sms * (1.0f / 8000.0f) + 0.5f * (accs[2] * (1.0f / (float)MSE_N));
  }
}

extern "C" void kernel_launch(void* const* d_in, const int* in_sizes, int n_in,
                              void* d_out, int out_size, void* d_ws, size_t ws_size,
                              hipStream_t stream) {
  const float* Zs  = (const float*)d_in[0];
  const int*   pos = (const int*)d_in[1];
  const int*   neg = (const int*)d_in[2];
  const float* fd  = (const float*)d_in[3];
  const float* idf = (const float*)d_in[4];
  float* out = (float*)d_out;

  char* ws = (char*)d_ws;
  u16*   Pc    = (u16*)(ws + 0);                 // 2,228,224 B
  u16*   Prow  = (u16*)(ws + 2228224);           // 2,228,224 B
  float* qpos  = (float*)(ws + 4456448);         // 32,768 B
  float* qneg  = (float*)(ws + 4489216);         // 32,768 B
  float* accs  = (float*)(ws + 4521984);         // 64 B
  float* S     = (float*)(ws + 4522048);         // 1,024 B  (zeroed)
  u16*   Gbf   = (u16*)(ws + 4523072);           // 69,632 B
  float* Gpart = (float*)(ws + 4592704);         // 1,048,576 B
  float* sdpos = (float*)(ws + 5641280);         // 32,768 B
  float* sdneg = (float*)(ws + 5674048);         // 32,768 B -> 5,706,816 total

  // zero Pc+Prow (pad correctness) and atomic targets (qpos,qneg,accs,S)
  hipMemsetAsync(d_ws, 0, 4523072, stream);
  gather_norm_k<<<8000, 128, 0, stream>>>(Zs, pos, neg, Pc, Prow);
  gsyrk_k<<<16, 256, 0, stream>>>(Pc, Gpart, S);
  reduceG_k<<<128, 256, 0, stream>>>(Gpart, Gbf);
  quad_k<<<dim3(64, 2), 256, 0, stream>>>(Gbf, Prow, S, qpos, qneg, sdpos, sdneg);
  mse_k<<<1024, 256, 0, stream>>>((const float4*)fd, (const float4*)idf, accs);
  persample_final_k<<<1, 1024, 0, stream>>>(qpos, qneg, sdpos, sdneg, accs, out);
}